// Round 1
// baseline (148.933 us; speedup 1.0000x reference)
//
#include <hip/hip_runtime.h>
#include <hip/hip_bf16.h>

#define BB 64
#define TT 512
#define HH 768
#define LL 9

// ---------------------------------------------------------------------------
// Kernel A: logits = relu(hidden @ W + b)   [32768 x 9]
// wave-per-4-rows, W^T staged in LDS, float4 loads of hidden.
// ---------------------------------------------------------------------------
__global__ __launch_bounds__(256) void logits_kernel(
    const float* __restrict__ hidden,   // [32768][768]
    const float* __restrict__ W,        // [768][9]
    const float* __restrict__ bias,     // [9]
    float* __restrict__ logits)         // [32768][9]
{
    __shared__ __align__(16) float WT[LL][HH];   // transposed W
    __shared__ float bsh[LL];

    const int tid = threadIdx.x;
    for (int idx = tid; idx < HH * LL; idx += 256) {
        int k = idx / LL, l = idx % LL;
        WT[l][k] = W[idx];
    }
    if (tid < LL) bsh[tid] = bias[tid];
    __syncthreads();

    const int wave = tid >> 6;
    const int lane = tid & 63;
    const long base_row = (long)blockIdx.x * 16 + wave * 4;
    const float* hrow = hidden + base_row * HH;

    float acc[4][LL];
#pragma unroll
    for (int r = 0; r < 4; ++r)
#pragma unroll
        for (int l = 0; l < LL; ++l) acc[r][l] = 0.f;

#pragma unroll
    for (int it = 0; it < 3; ++it) {
        const int k = it * 256 + lane * 4;
        float4 h[4];
#pragma unroll
        for (int r = 0; r < 4; ++r)
            h[r] = *(const float4*)(hrow + (long)r * HH + k);
#pragma unroll
        for (int l = 0; l < LL; ++l) {
            float4 w4 = *(const float4*)(&WT[l][k]);
#pragma unroll
            for (int r = 0; r < 4; ++r) {
                acc[r][l] += h[r].x * w4.x + h[r].y * w4.y
                           + h[r].z * w4.z + h[r].w * w4.w;
            }
        }
    }

    // butterfly reduce each of the 36 sums across the 64 lanes
#pragma unroll
    for (int r = 0; r < 4; ++r)
#pragma unroll
        for (int l = 0; l < LL; ++l) {
            float v = acc[r][l];
#pragma unroll
            for (int off = 32; off; off >>= 1) v += __shfl_xor(v, off, 64);
            acc[r][l] = v;
        }

    if (lane < LL) {
#pragma unroll
        for (int r = 0; r < 4; ++r) {
            float v = acc[r][0];
#pragma unroll
            for (int l = 1; l < LL; ++l) v = (lane == l) ? acc[r][l] : v;
            v += bsh[lane];
            v = v > 0.f ? v : 0.f;
            logits[(base_row + r) * LL + lane] = v;
        }
    }
}

// ---------------------------------------------------------------------------
// Kernel B: per-batch CRF.  Block = 128 threads (2 waves).
//   wave 0: unary/binary partials + logsumexp forward scan -> ll[b]
//   wave 1: Viterbi forward (backpointers) + parallel compose backtrace
// ---------------------------------------------------------------------------
__global__ __launch_bounds__(128) void crf_kernel(
    const float* __restrict__ logits,   // [64][512][9]
    const float* __restrict__ trans,    // [9][9]
    const int*  __restrict__ tags,      // [64][512]
    const int*  __restrict__ lengths,   // [64]
    float* __restrict__ ll,             // [64]
    float* __restrict__ out_decode)     // [64][512] (floats)
{
    const int b    = blockIdx.x;
    const int tid  = threadIdx.x;
    const int wave = tid >> 6;
    const int lane = tid & 63;

    __shared__ float lg[TT][LL];
    __shared__ int   tg[TT];
    __shared__ unsigned char bpB[TT][LL];
    __shared__ float trS[LL * LL];
    __shared__ float score_parts[4];

    const int len = lengths[b];
    const float* lgg = logits + (size_t)b * TT * LL;
    for (int idx = tid; idx < TT * LL; idx += 128) lg[idx / LL][idx % LL] = lgg[idx];
    const int* tgg = tags + (size_t)b * TT;
    for (int t = tid; t < TT; t += 128) tg[t] = tgg[t];
    for (int idx = tid; idx < LL * LL; idx += 128) trS[idx] = trans[idx];
    __syncthreads();

    // ---- unary + binary gold scores (parallel over t, both waves) ----
    float u = 0.f, bs = 0.f;
    for (int t = tid; t < len; t += 128) u += lg[t][tg[t]];
    for (int t = tid + 1; t < len; t += 128) bs += trS[tg[t - 1] * LL + tg[t]];
#pragma unroll
    for (int off = 32; off; off >>= 1) {
        u  += __shfl_xor(u, off, 64);
        bs += __shfl_xor(bs, off, 64);
    }
    if (lane == 0) { score_parts[wave * 2] = u; score_parts[wave * 2 + 1] = bs; }
    __syncthreads();

    const int j = (lane < LL) ? lane : (LL - 1);
    float trc[LL];                 // transitions column j
#pragma unroll
    for (int i = 0; i < LL; ++i) trc[i] = trS[i * LL + j];

    if (wave == 0) {
        // ---------------- logsumexp forward scan ----------------
        float alpha[LL];
#pragma unroll
        for (int i = 0; i < LL; ++i) alpha[i] = lg[0][i];

        for (int t = 1; t < len; ++t) {
            float s[LL];
#pragma unroll
            for (int i = 0; i < LL; ++i) s[i] = alpha[i] + trc[i];
            float m = fmaxf(fmaxf(fmaxf(fmaxf(s[0], s[1]), fmaxf(s[2], s[3])),
                                  fmaxf(fmaxf(s[4], s[5]), fmaxf(s[6], s[7]))),
                            s[8]);
            float sum = 0.f;
#pragma unroll
            for (int i = 0; i < LL; ++i) sum += __expf(s[i] - m);
            float na = m + __logf(sum) + lg[t][j];
#pragma unroll
            for (int i = 0; i < LL; ++i) alpha[i] = __shfl(na, i, 64);
        }
        float m = fmaxf(fmaxf(fmaxf(fmaxf(alpha[0], alpha[1]), fmaxf(alpha[2], alpha[3])),
                              fmaxf(fmaxf(alpha[4], alpha[5]), fmaxf(alpha[6], alpha[7]))),
                        alpha[8]);
        float sum = 0.f;
#pragma unroll
        for (int i = 0; i < LL; ++i) sum += __expf(alpha[i] - m);
        float log_norm = m + __logf(sum);
        if (lane == 0) {
            float unary  = score_parts[0] + score_parts[2];
            float binary = score_parts[1] + score_parts[3];
            ll[b] = unary + binary - log_norm;
        }
    } else {
        // ---------------- Viterbi forward ----------------
        float st[LL];
#pragma unroll
        for (int i = 0; i < LL; ++i) st[i] = lg[0][i];

        for (int t = 1; t < len; ++t) {
            float best = st[0] + trc[0];
            int bi = 0;
#pragma unroll
            for (int i = 1; i < LL; ++i) {
                float v = st[i] + trc[i];
                if (v > best) { best = v; bi = i; }   // first-max kept
            }
            if (lane < LL) bpB[t][lane] = (unsigned char)bi;
            float ns = best + lg[t][j];
#pragma unroll
            for (int i = 0; i < LL; ++i) st[i] = __shfl(ns, i, 64);
        }

        // last_tag = first-max argmax of final state (replicated in all lanes)
        float bestv = st[0];
        int last_tag = 0;
#pragma unroll
        for (int i = 1; i < LL; ++i)
            if (st[i] > bestv) { bestv = st[i]; last_tag = i; }

        // ---------------- compose-based parallel backtrace ----------------
        const unsigned long long IDENT = 0x876543210ULL;
        unsigned long long f[8];
        const int t0 = lane * 8;
#pragma unroll
        for (int m2 = 0; m2 < 8; ++m2) {
            int t = t0 + m2;
            unsigned long long F = IDENT;
            if (t >= 1 && t < len) {
                F = 0ULL;
#pragma unroll
                for (int jj = 0; jj < LL; ++jj)
                    F |= ((unsigned long long)bpB[t][jj]) << (4 * jj);
            }
            f[m2] = F;
        }
        // chunk composition h = f[0] o f[1] o ... o f[7]
        unsigned long long h = f[7];
#pragma unroll
        for (int m2 = 6; m2 >= 0; --m2) {
            unsigned long long hn = 0ULL;
#pragma unroll
            for (int jj = 0; jj < LL; ++jj) {
                int v = (int)((h >> (4 * jj)) & 15ULL);
                int w = (int)((f[m2] >> (4 * v)) & 15ULL);
                hn |= ((unsigned long long)w) << (4 * jj);
            }
            h = hn;
        }
        // serial chunk-boundary walk (all lanes redundantly)
        int tag = last_tag;
        int entry = last_tag;
        for (int l2 = 63; l2 >= 0; --l2) {
            unsigned long long g = __shfl(h, l2, 64);
            if (l2 == lane) entry = tag;
            tag = (int)((g >> (4 * tag)) & 15ULL);
        }
        // walk own 8-step chunk, emitting decode
        float* dec = out_decode + (size_t)b * TT;
        int e = entry;
        {
            int t = t0 + 7;
            dec[t] = (t < len) ? (float)e : 0.f;
        }
#pragma unroll
        for (int m2 = 7; m2 >= 1; --m2) {
            e = (int)((f[m2] >> (4 * e)) & 15ULL);
            int t = t0 + m2 - 1;
            dec[t] = (t < len) ? (float)e : 0.f;
        }
    }
}

// ---------------------------------------------------------------------------
// Kernel C: loss = -mean(ll)
// ---------------------------------------------------------------------------
__global__ __launch_bounds__(64) void loss_kernel(const float* __restrict__ ll,
                                                  float* __restrict__ out)
{
    const int lane = threadIdx.x;
    float v = ll[lane];
#pragma unroll
    for (int off = 32; off; off >>= 1) v += __shfl_xor(v, off, 64);
    if (lane == 0) out[0] = -v * (1.0f / 64.0f);
}

extern "C" void kernel_launch(void* const* d_in, const int* in_sizes, int n_in,
                              void* d_out, int out_size, void* d_ws, size_t ws_size,
                              hipStream_t stream)
{
    const float* hidden  = (const float*)d_in[0];
    const float* W       = (const float*)d_in[1];
    const float* bias    = (const float*)d_in[2];
    const float* trans   = (const float*)d_in[3];
    const int*   tags    = (const int*)d_in[4];
    const int*   lengths = (const int*)d_in[5];

    float* out = (float*)d_out;
    float* logits = (float*)d_ws;                       // 32768*9 floats
    float* ll     = logits + (size_t)BB * TT * LL;      // 64 floats

    logits_kernel<<<2048, 256, 0, stream>>>(hidden, W, bias, logits);
    crf_kernel<<<BB, 128, 0, stream>>>(logits, trans, tags, lengths, ll, out + 1);
    loss_kernel<<<1, 64, 0, stream>>>(ll, out);
}